// Round 1
// baseline (128.225 us; speedup 1.0000x reference)
//
#include <hip/hip_runtime.h>

// DistMult forward scoring:
//   score[e] = sum_d h[src[e],d] * fwd_rel[etype[e],d] * h[dst[e],d]
// E=640000, D=128, fp32. Cache-gather-bound (working set ~15 MB << LLC).
//
// Layout: half-wave (32 lanes) per edge; lane loads float4 (16 B) so one
// gathered 512 B row == one fully coalesced wave access. Width-32 shuffle
// reduction, lane 0 of each half-wave writes.

constexpr int EMB_DIM = 128;

__global__ __launch_bounds__(256) void distmult_score_kernel(
    const float* __restrict__ h,
    const int*   __restrict__ src,
    const int*   __restrict__ dst,
    const int*   __restrict__ etype,
    const float* __restrict__ fwd_rel,
    float*       __restrict__ out,
    int n_edges)
{
    const int tid  = blockIdx.x * blockDim.x + threadIdx.x;
    const int lane = threadIdx.x & 63;
    const int half = lane >> 5;          // which half-wave (0/1)
    const int sub  = lane & 31;          // lane within half-wave
    const int edge = (tid >> 6) * 2 + half;
    if (edge >= n_edges) return;         // whole half-wave exits together

    const int s = src[edge];
    const int d = dst[edge];
    const int e = etype[edge];

    const float4* hu = reinterpret_cast<const float4*>(h       + (size_t)s * EMB_DIM);
    const float4* hv = reinterpret_cast<const float4*>(h       + (size_t)d * EMB_DIM);
    const float4* wr = reinterpret_cast<const float4*>(fwd_rel + (size_t)e * EMB_DIM);

    const float4 a = hu[sub];
    const float4 b = wr[sub];
    const float4 c = hv[sub];

    float acc = a.x * b.x * c.x
              + a.y * b.y * c.y
              + a.z * b.z * c.z
              + a.w * b.w * c.w;

    // reduce across the 32 lanes of this half-wave
    #pragma unroll
    for (int off = 16; off > 0; off >>= 1)
        acc += __shfl_down(acc, off, 32);

    if (sub == 0) out[edge] = acc;
}

extern "C" void kernel_launch(void* const* d_in, const int* in_sizes, int n_in,
                              void* d_out, int out_size, void* d_ws, size_t ws_size,
                              hipStream_t stream) {
    const float* h       = (const float*)d_in[0];
    const int*   src     = (const int*)d_in[1];
    const int*   dst     = (const int*)d_in[2];
    const int*   etype   = (const int*)d_in[3];
    const float* fwd_rel = (const float*)d_in[4];
    // d_in[5] = rev_rel, unused in forward-direction scoring
    float* out = (float*)d_out;

    const int n_edges = in_sizes[1];
    const int edges_per_block = 8;  // 256 threads = 4 waves = 8 half-waves
    const int grid = (n_edges + edges_per_block - 1) / edges_per_block;

    distmult_score_kernel<<<grid, 256, 0, stream>>>(
        h, src, dst, etype, fwd_rel, out, n_edges);
}

// Round 2
// 111.948 us; speedup vs baseline: 1.1454x; 1.1454x over previous
//
#include <hip/hip_runtime.h>

// DistMult forward scoring: score[e] = sum_d h[src,d] * fwd_rel[et,d] * h[dst,d]
// E=640000, D=128, fp32.
//
// R1 strategy: split D into two 64-dim halves and steer each half to a fixed
// set of XCDs (blockIdx % 8 round-robin heuristic). Per-XCD gather footprint:
// 2.56 MB (h half) + 128 KB (fwd_rel half) < 4 MiB L2 -> near-zero capacity
// misses. Team = 16 lanes x float4 = 256 B per gathered half-row (coalesced).
// 2 edges per team for load ILP. Partials -> d_ws, combined by add kernel.

constexpr int EMB_DIM  = 128;
constexpr int HALF_DIM = 64;

__global__ __launch_bounds__(256) void distmult_half_kernel(
    const float* __restrict__ h,
    const int*   __restrict__ src,
    const int*   __restrict__ dst,
    const int*   __restrict__ etype,
    const float* __restrict__ fwd_rel,
    float*       __restrict__ partial,   // [2][n_edges]
    int n_edges)
{
    const int b    = blockIdx.x;
    const int g    = b >> 3;
    const int r    = b & 7;
    const int half = (r >= 4);           // XCDs 0-3 -> low dims, 4-7 -> high
    const int idx  = g * 4 + (r & 3);    // block index within this half

    const int team = threadIdx.x >> 4;   // 16 teams of 16 lanes
    const int lane = threadIdx.x & 15;

    const int e0 = idx * 32 + team * 2;  // 2 edges per team
    const int e1 = e0 + 1;
    if (e0 >= n_edges) return;

    const int doff = half * HALF_DIM + lane * 4;

    const int s0 = src[e0];
    const int d0 = dst[e0];
    const int t0 = etype[e0];

    float4 a0, b0, c0;
    a0 = *reinterpret_cast<const float4*>(h       + (size_t)s0 * EMB_DIM + doff);
    b0 = *reinterpret_cast<const float4*>(fwd_rel + (size_t)t0 * EMB_DIM + doff);
    c0 = *reinterpret_cast<const float4*>(h       + (size_t)d0 * EMB_DIM + doff);

    float acc0 = a0.x * b0.x * c0.x + a0.y * b0.y * c0.y
               + a0.z * b0.z * c0.z + a0.w * b0.w * c0.w;

    float acc1 = 0.0f;
    const bool has1 = (e1 < n_edges);
    if (has1) {
        const int s1 = src[e1];
        const int d1 = dst[e1];
        const int t1 = etype[e1];
        float4 a1 = *reinterpret_cast<const float4*>(h       + (size_t)s1 * EMB_DIM + doff);
        float4 b1 = *reinterpret_cast<const float4*>(fwd_rel + (size_t)t1 * EMB_DIM + doff);
        float4 c1 = *reinterpret_cast<const float4*>(h       + (size_t)d1 * EMB_DIM + doff);
        acc1 = a1.x * b1.x * c1.x + a1.y * b1.y * c1.y
             + a1.z * b1.z * c1.z + a1.w * b1.w * c1.w;
    }

    // reduce across the 16 lanes of the team
    #pragma unroll
    for (int off = 8; off > 0; off >>= 1) {
        acc0 += __shfl_down(acc0, off, 16);
        acc1 += __shfl_down(acc1, off, 16);
    }

    if (lane == 0) {
        float* p = partial + (size_t)half * n_edges;
        p[e0] = acc0;
        if (has1) p[e1] = acc1;
    }
}

__global__ __launch_bounds__(256) void combine_kernel(
    const float* __restrict__ p, float* __restrict__ out, int n_edges)
{
    const int n4 = n_edges >> 2;  // n_edges divisible by 4 here; tail handled below
    const float4* p0 = reinterpret_cast<const float4*>(p);
    const float4* p1 = reinterpret_cast<const float4*>(p + n_edges);
    float4* o = reinterpret_cast<float4*>(out);
    for (int i = blockIdx.x * blockDim.x + threadIdx.x; i < n4;
         i += gridDim.x * blockDim.x) {
        float4 x = p0[i], y = p1[i];
        o[i] = make_float4(x.x + y.x, x.y + y.y, x.z + y.z, x.w + y.w);
    }
    // scalar tail
    for (int i = (n4 << 2) + blockIdx.x * blockDim.x + threadIdx.x; i < n_edges;
         i += gridDim.x * blockDim.x) {
        out[i] = p[i] + p[n_edges + i];
    }
}

// fallback (R0 kernel) if d_ws is too small for partials
__global__ __launch_bounds__(256) void distmult_score_kernel(
    const float* __restrict__ h,
    const int*   __restrict__ src,
    const int*   __restrict__ dst,
    const int*   __restrict__ etype,
    const float* __restrict__ fwd_rel,
    float*       __restrict__ out,
    int n_edges)
{
    const int tid  = blockIdx.x * blockDim.x + threadIdx.x;
    const int lane = threadIdx.x & 63;
    const int half = lane >> 5;
    const int sub  = lane & 31;
    const int edge = (tid >> 6) * 2 + half;
    if (edge >= n_edges) return;

    const int s = src[edge];
    const int d = dst[edge];
    const int e = etype[edge];

    const float4 a = reinterpret_cast<const float4*>(h       + (size_t)s * EMB_DIM)[sub];
    const float4 b = reinterpret_cast<const float4*>(fwd_rel + (size_t)e * EMB_DIM)[sub];
    const float4 c = reinterpret_cast<const float4*>(h       + (size_t)d * EMB_DIM)[sub];

    float acc = a.x * b.x * c.x + a.y * b.y * c.y
              + a.z * b.z * c.z + a.w * b.w * c.w;
    #pragma unroll
    for (int off = 16; off > 0; off >>= 1)
        acc += __shfl_down(acc, off, 32);
    if (sub == 0) out[edge] = acc;
}

extern "C" void kernel_launch(void* const* d_in, const int* in_sizes, int n_in,
                              void* d_out, int out_size, void* d_ws, size_t ws_size,
                              hipStream_t stream) {
    const float* h       = (const float*)d_in[0];
    const int*   src     = (const int*)d_in[1];
    const int*   dst     = (const int*)d_in[2];
    const int*   etype   = (const int*)d_in[3];
    const float* fwd_rel = (const float*)d_in[4];
    float* out = (float*)d_out;

    const int n_edges = in_sizes[1];
    const size_t need = (size_t)2 * n_edges * sizeof(float);

    if (ws_size >= need) {
        float* partial = (float*)d_ws;
        const int blocks_per_half = (n_edges + 31) / 32;   // 32 edges/block
        const int groups = (blocks_per_half + 3) / 4;      // 4 same-half blocks per group of 8
        const int grid = groups * 8;
        distmult_half_kernel<<<grid, 256, 0, stream>>>(
            h, src, dst, etype, fwd_rel, partial, n_edges);
        const int cgrid = ((n_edges / 4) + 255) / 256;
        combine_kernel<<<cgrid, 256, 0, stream>>>(partial, out, n_edges);
    } else {
        const int grid = (n_edges + 7) / 8;
        distmult_score_kernel<<<grid, 256, 0, stream>>>(
            h, src, dst, etype, fwd_rel, out, n_edges);
    }
}

// Round 3
// 111.259 us; speedup vs baseline: 1.1525x; 1.0062x over previous
//
#include <hip/hip_runtime.h>

// DistMult forward scoring: score[e] = sum_d h[src,d] * fwd_rel[et,d] * h[dst,d]
// E=640000, D=128, fp32.
//
// R2: XCD dim-split (as R1: blockIdx%8 -> XCDs 0-3 do dims 0-63, 4-7 do 64-127;
// per-XCD gather footprint 2.7 MB < 4 MiB L2) + raised memory-level
// parallelism: each 16-lane team processes 4 edges, issuing all 12 index
// loads then all 12 float4 gathers before any use. Lane 0 stores a float4 of
// partials. Combine kernel adds the two halves.

constexpr int EMB_DIM  = 128;
constexpr int HALF_DIM = 64;

__global__ __launch_bounds__(256) void distmult_half_kernel(
    const float* __restrict__ h,
    const int*   __restrict__ src,
    const int*   __restrict__ dst,
    const int*   __restrict__ etype,
    const float* __restrict__ fwd_rel,
    float*       __restrict__ partial,   // [2][n_edges]
    int n_edges)
{
    const int b    = blockIdx.x;
    const int g    = b >> 3;
    const int r    = b & 7;
    const int half = (r >= 4);           // XCDs 0-3 -> low dims, 4-7 -> high
    const int idx  = g * 4 + (r & 3);    // block index within this half

    const int team = threadIdx.x >> 4;   // 16 teams of 16 lanes
    const int lane = threadIdx.x & 15;

    const int e0 = idx * 64 + team * 4;  // 4 edges per team
    if (e0 >= n_edges) return;

    const int doff = half * HALF_DIM + lane * 4;
    const float* hp = h + doff;
    const float* wp = fwd_rel + doff;

    float acc[4] = {0.f, 0.f, 0.f, 0.f};

    if (e0 + 3 < n_edges) {
        // fast path: load all 12 indices, then all 12 gathers (12 outstanding)
        int s0 = src[e0],   s1 = src[e0+1],   s2 = src[e0+2],   s3 = src[e0+3];
        int d0 = dst[e0],   d1 = dst[e0+1],   d2 = dst[e0+2],   d3 = dst[e0+3];
        int t0 = etype[e0], t1 = etype[e0+1], t2 = etype[e0+2], t3 = etype[e0+3];

        float4 a0 = *reinterpret_cast<const float4*>(hp + (size_t)s0 * EMB_DIM);
        float4 a1 = *reinterpret_cast<const float4*>(hp + (size_t)s1 * EMB_DIM);
        float4 a2 = *reinterpret_cast<const float4*>(hp + (size_t)s2 * EMB_DIM);
        float4 a3 = *reinterpret_cast<const float4*>(hp + (size_t)s3 * EMB_DIM);
        float4 c0 = *reinterpret_cast<const float4*>(hp + (size_t)d0 * EMB_DIM);
        float4 c1 = *reinterpret_cast<const float4*>(hp + (size_t)d1 * EMB_DIM);
        float4 c2 = *reinterpret_cast<const float4*>(hp + (size_t)d2 * EMB_DIM);
        float4 c3 = *reinterpret_cast<const float4*>(hp + (size_t)d3 * EMB_DIM);
        float4 b0 = *reinterpret_cast<const float4*>(wp + (size_t)t0 * EMB_DIM);
        float4 b1 = *reinterpret_cast<const float4*>(wp + (size_t)t1 * EMB_DIM);
        float4 b2 = *reinterpret_cast<const float4*>(wp + (size_t)t2 * EMB_DIM);
        float4 b3 = *reinterpret_cast<const float4*>(wp + (size_t)t3 * EMB_DIM);

        acc[0] = a0.x*b0.x*c0.x + a0.y*b0.y*c0.y + a0.z*b0.z*c0.z + a0.w*b0.w*c0.w;
        acc[1] = a1.x*b1.x*c1.x + a1.y*b1.y*c1.y + a1.z*b1.z*c1.z + a1.w*b1.w*c1.w;
        acc[2] = a2.x*b2.x*c2.x + a2.y*b2.y*c2.y + a2.z*b2.z*c2.z + a2.w*b2.w*c2.w;
        acc[3] = a3.x*b3.x*c3.x + a3.y*b3.y*c3.y + a3.z*b3.z*c3.z + a3.w*b3.w*c3.w;
    } else {
        for (int k = 0; k < 4; ++k) {
            int e = e0 + k;
            if (e >= n_edges) break;
            int s = src[e], d = dst[e], t = etype[e];
            float4 a = *reinterpret_cast<const float4*>(hp + (size_t)s * EMB_DIM);
            float4 bb = *reinterpret_cast<const float4*>(wp + (size_t)t * EMB_DIM);
            float4 c = *reinterpret_cast<const float4*>(hp + (size_t)d * EMB_DIM);
            acc[k] = a.x*bb.x*c.x + a.y*bb.y*c.y + a.z*bb.z*c.z + a.w*bb.w*c.w;
        }
    }

    // reduce across the 16 lanes of the team
    #pragma unroll
    for (int off = 8; off > 0; off >>= 1) {
        acc[0] += __shfl_down(acc[0], off, 16);
        acc[1] += __shfl_down(acc[1], off, 16);
        acc[2] += __shfl_down(acc[2], off, 16);
        acc[3] += __shfl_down(acc[3], off, 16);
    }

    if (lane == 0) {
        float* p = partial + (size_t)half * n_edges;
        if (e0 + 3 < n_edges) {
            *reinterpret_cast<float4*>(p + e0) =
                make_float4(acc[0], acc[1], acc[2], acc[3]);
        } else {
            for (int k = 0; k < 4 && e0 + k < n_edges; ++k) p[e0 + k] = acc[k];
        }
    }
}

__global__ __launch_bounds__(256) void combine_kernel(
    const float* __restrict__ p, float* __restrict__ out, int n_edges)
{
    const int n4 = n_edges >> 2;
    const float4* p0 = reinterpret_cast<const float4*>(p);
    const float4* p1 = reinterpret_cast<const float4*>(p + n_edges);
    float4* o = reinterpret_cast<float4*>(out);
    for (int i = blockIdx.x * blockDim.x + threadIdx.x; i < n4;
         i += gridDim.x * blockDim.x) {
        float4 x = p0[i], y = p1[i];
        o[i] = make_float4(x.x + y.x, x.y + y.y, x.z + y.z, x.w + y.w);
    }
    for (int i = (n4 << 2) + blockIdx.x * blockDim.x + threadIdx.x; i < n_edges;
         i += gridDim.x * blockDim.x) {
        out[i] = p[i] + p[n_edges + i];
    }
}

// fallback if d_ws too small for partials
__global__ __launch_bounds__(256) void distmult_score_kernel(
    const float* __restrict__ h,
    const int*   __restrict__ src,
    const int*   __restrict__ dst,
    const int*   __restrict__ etype,
    const float* __restrict__ fwd_rel,
    float*       __restrict__ out,
    int n_edges)
{
    const int tid  = blockIdx.x * blockDim.x + threadIdx.x;
    const int lane = threadIdx.x & 63;
    const int half = lane >> 5;
    const int sub  = lane & 31;
    const int edge = (tid >> 6) * 2 + half;
    if (edge >= n_edges) return;

    const int s = src[edge];
    const int d = dst[edge];
    const int e = etype[edge];

    const float4 a = reinterpret_cast<const float4*>(h       + (size_t)s * EMB_DIM)[sub];
    const float4 b = reinterpret_cast<const float4*>(fwd_rel + (size_t)e * EMB_DIM)[sub];
    const float4 c = reinterpret_cast<const float4*>(h       + (size_t)d * EMB_DIM)[sub];

    float acc = a.x*b.x*c.x + a.y*b.y*c.y + a.z*b.z*c.z + a.w*b.w*c.w;
    #pragma unroll
    for (int off = 16; off > 0; off >>= 1)
        acc += __shfl_down(acc, off, 32);
    if (sub == 0) out[edge] = acc;
}

extern "C" void kernel_launch(void* const* d_in, const int* in_sizes, int n_in,
                              void* d_out, int out_size, void* d_ws, size_t ws_size,
                              hipStream_t stream) {
    const float* h       = (const float*)d_in[0];
    const int*   src     = (const int*)d_in[1];
    const int*   dst     = (const int*)d_in[2];
    const int*   etype   = (const int*)d_in[3];
    const float* fwd_rel = (const float*)d_in[4];
    float* out = (float*)d_out;

    const int n_edges = in_sizes[1];
    const size_t need = (size_t)2 * n_edges * sizeof(float);

    if (ws_size >= need) {
        float* partial = (float*)d_ws;
        const int blocks_per_half = (n_edges + 63) / 64;   // 64 edges/block
        const int groups = (blocks_per_half + 3) / 4;
        const int grid = groups * 8;
        distmult_half_kernel<<<grid, 256, 0, stream>>>(
            h, src, dst, etype, fwd_rel, partial, n_edges);
        const int cgrid = ((n_edges / 4) + 255) / 256;
        combine_kernel<<<cgrid, 256, 0, stream>>>(partial, out, n_edges);
    } else {
        const int grid = (n_edges + 7) / 8;
        distmult_score_kernel<<<grid, 256, 0, stream>>>(
            h, src, dst, etype, fwd_rel, out, n_edges);
    }
}

// Round 4
// 106.959 us; speedup vs baseline: 1.1988x; 1.0402x over previous
//
#include <hip/hip_runtime.h>

// DistMult forward scoring: score[e] = sum_d h[src,d] * fwd_rel[et,d] * h[dst,d]
// E=640000, D=128, fp32.
//
// R3: we measured gather delivery pinned at ~20 TB/s = 8 XCD x 16 L2 ch x
// 64 B x 2.4 GHz (L2 channel ceiling). Fix: remove the fwd_rel gather (1/3 of
// bytes) from the L2 path by staging the per-half fwd_rel slice (500x64x4 =
// 125 KB) in LDS, served by ds_read_b128. Keep R1's XCD dim-split
// (blockIdx%8: XCDs 0-3 dims 0-63, XCDs 4-7 dims 64-127) so per-XCD h
// footprint (2.56 MB) stays L2-resident. 1024-thread blocks, grid=256
// (1 block/CU), grid-stride edge loop. Index loads vectorized to int4
// (3 vmem instrs per 4 edges instead of 12).

constexpr int EMB_DIM      = 128;
constexpr int HALF_DIM     = 64;
constexpr int MAX_RELS     = 500;
constexpr int BLOCKS_TOTAL = 256;             // 128 per dim-half
constexpr int BLK_THREADS  = 1024;            // 64 teams of 16 lanes

__global__ __launch_bounds__(BLK_THREADS) void distmult_lds_kernel(
    const float* __restrict__ h,
    const int*   __restrict__ src,
    const int*   __restrict__ dst,
    const int*   __restrict__ etype,
    const float* __restrict__ fwd_rel,
    float*       __restrict__ partial,   // [2][n_edges]
    int n_edges, int n_rels)
{
    __shared__ float w_lds[MAX_RELS * HALF_DIM];   // 125 KB for 500 rels

    const int b    = blockIdx.x;
    const int g    = b >> 3;
    const int r    = b & 7;
    const int half = (r >= 4);           // XCDs 0-3 -> low dims, 4-7 -> high
    const int idx  = g * 4 + (r & 3);    // block index within this half [0,128)

    // ---- stage fwd_rel half-columns into LDS (coalesced float4) ----
    {
        const int slots = n_rels * (HALF_DIM / 4);       // float4 slots
        for (int s = threadIdx.x; s < slots; s += BLK_THREADS) {
            const int row = s >> 4;
            const int c   = s & 15;
            float4 v = *reinterpret_cast<const float4*>(
                fwd_rel + (size_t)row * EMB_DIM + half * HALF_DIM + c * 4);
            *reinterpret_cast<float4*>(w_lds + row * HALF_DIM + c * 4) = v;
        }
    }
    __syncthreads();

    const int team = threadIdx.x >> 4;   // 64 teams
    const int lane = threadIdx.x & 15;

    const float* hp = h + half * HALF_DIM + lane * 4;
    const float* wl = w_lds + lane * 4;
    float* p = partial + (size_t)half * n_edges;

    const int stride = (BLOCKS_TOTAL / 2) * (BLK_THREADS / 16) * 4;  // 32768

    for (int e0 = idx * (BLK_THREADS / 16) * 4 + team * 4; e0 < n_edges;
         e0 += stride) {
        if (e0 + 3 < n_edges) {
            // 3 int4 index loads covering 4 edges each
            const int4 s4 = *reinterpret_cast<const int4*>(src   + e0);
            const int4 d4 = *reinterpret_cast<const int4*>(dst   + e0);
            const int4 t4 = *reinterpret_cast<const int4*>(etype + e0);

            // 8 h-gathers (the only L2-path gathers now)
            float4 a0 = *reinterpret_cast<const float4*>(hp + (size_t)s4.x * EMB_DIM);
            float4 a1 = *reinterpret_cast<const float4*>(hp + (size_t)s4.y * EMB_DIM);
            float4 a2 = *reinterpret_cast<const float4*>(hp + (size_t)s4.z * EMB_DIM);
            float4 a3 = *reinterpret_cast<const float4*>(hp + (size_t)s4.w * EMB_DIM);
            float4 c0 = *reinterpret_cast<const float4*>(hp + (size_t)d4.x * EMB_DIM);
            float4 c1 = *reinterpret_cast<const float4*>(hp + (size_t)d4.y * EMB_DIM);
            float4 c2 = *reinterpret_cast<const float4*>(hp + (size_t)d4.z * EMB_DIM);
            float4 c3 = *reinterpret_cast<const float4*>(hp + (size_t)d4.w * EMB_DIM);

            // 4 w-reads from LDS
            float4 b0 = *reinterpret_cast<const float4*>(wl + (size_t)t4.x * HALF_DIM);
            float4 b1 = *reinterpret_cast<const float4*>(wl + (size_t)t4.y * HALF_DIM);
            float4 b2 = *reinterpret_cast<const float4*>(wl + (size_t)t4.z * HALF_DIM);
            float4 b3 = *reinterpret_cast<const float4*>(wl + (size_t)t4.w * HALF_DIM);

            float acc0 = a0.x*b0.x*c0.x + a0.y*b0.y*c0.y + a0.z*b0.z*c0.z + a0.w*b0.w*c0.w;
            float acc1 = a1.x*b1.x*c1.x + a1.y*b1.y*c1.y + a1.z*b1.z*c1.z + a1.w*b1.w*c1.w;
            float acc2 = a2.x*b2.x*c2.x + a2.y*b2.y*c2.y + a2.z*b2.z*c2.z + a2.w*b2.w*c2.w;
            float acc3 = a3.x*b3.x*c3.x + a3.y*b3.y*c3.y + a3.z*b3.z*c3.z + a3.w*b3.w*c3.w;

            #pragma unroll
            for (int off = 8; off > 0; off >>= 1) {
                acc0 += __shfl_down(acc0, off, 16);
                acc1 += __shfl_down(acc1, off, 16);
                acc2 += __shfl_down(acc2, off, 16);
                acc3 += __shfl_down(acc3, off, 16);
            }
            if (lane == 0)
                *reinterpret_cast<float4*>(p + e0) =
                    make_float4(acc0, acc1, acc2, acc3);
        } else {
            for (int k = 0; k < 4; ++k) {
                const int e = e0 + k;
                if (e >= n_edges) break;
                const int s = src[e], d = dst[e], t = etype[e];
                float4 a  = *reinterpret_cast<const float4*>(hp + (size_t)s * EMB_DIM);
                float4 c  = *reinterpret_cast<const float4*>(hp + (size_t)d * EMB_DIM);
                float4 bb = *reinterpret_cast<const float4*>(wl + (size_t)t * HALF_DIM);
                float acc = a.x*bb.x*c.x + a.y*bb.y*c.y + a.z*bb.z*c.z + a.w*bb.w*c.w;
                #pragma unroll
                for (int off = 8; off > 0; off >>= 1)
                    acc += __shfl_down(acc, off, 16);
                if (lane == 0) p[e] = acc;
            }
        }
    }
}

__global__ __launch_bounds__(256) void combine_kernel(
    const float* __restrict__ p, float* __restrict__ out, int n_edges)
{
    const int n4 = n_edges >> 2;
    const float4* p0 = reinterpret_cast<const float4*>(p);
    const float4* p1 = reinterpret_cast<const float4*>(p + n_edges);
    float4* o = reinterpret_cast<float4*>(out);
    for (int i = blockIdx.x * blockDim.x + threadIdx.x; i < n4;
         i += gridDim.x * blockDim.x) {
        float4 x = p0[i], y = p1[i];
        o[i] = make_float4(x.x + y.x, x.y + y.y, x.z + y.z, x.w + y.w);
    }
    for (int i = (n4 << 2) + blockIdx.x * blockDim.x + threadIdx.x; i < n_edges;
         i += gridDim.x * blockDim.x) {
        out[i] = p[i] + p[n_edges + i];
    }
}

// fallback: R2-style kernel (no LDS staging) if ws too small or n_rels > 500
__global__ __launch_bounds__(256) void distmult_score_kernel(
    const float* __restrict__ h,
    const int*   __restrict__ src,
    const int*   __restrict__ dst,
    const int*   __restrict__ etype,
    const float* __restrict__ fwd_rel,
    float*       __restrict__ out,
    int n_edges)
{
    const int tid  = blockIdx.x * blockDim.x + threadIdx.x;
    const int lane = threadIdx.x & 63;
    const int half = lane >> 5;
    const int sub  = lane & 31;
    const int edge = (tid >> 6) * 2 + half;
    if (edge >= n_edges) return;

    const int s = src[edge];
    const int d = dst[edge];
    const int e = etype[edge];

    const float4 a = reinterpret_cast<const float4*>(h       + (size_t)s * EMB_DIM)[sub];
    const float4 b = reinterpret_cast<const float4*>(fwd_rel + (size_t)e * EMB_DIM)[sub];
    const float4 c = reinterpret_cast<const float4*>(h       + (size_t)d * EMB_DIM)[sub];

    float acc = a.x*b.x*c.x + a.y*b.y*c.y + a.z*b.z*c.z + a.w*b.w*c.w;
    #pragma unroll
    for (int off = 16; off > 0; off >>= 1)
        acc += __shfl_down(acc, off, 32);
    if (sub == 0) out[edge] = acc;
}

extern "C" void kernel_launch(void* const* d_in, const int* in_sizes, int n_in,
                              void* d_out, int out_size, void* d_ws, size_t ws_size,
                              hipStream_t stream) {
    const float* h       = (const float*)d_in[0];
    const int*   src     = (const int*)d_in[1];
    const int*   dst     = (const int*)d_in[2];
    const int*   etype   = (const int*)d_in[3];
    const float* fwd_rel = (const float*)d_in[4];
    float* out = (float*)d_out;

    const int n_edges = in_sizes[1];
    const int n_rels  = in_sizes[4] / EMB_DIM;
    const size_t need = (size_t)2 * n_edges * sizeof(float);

    if (ws_size >= need && n_rels <= MAX_RELS) {
        float* partial = (float*)d_ws;
        distmult_lds_kernel<<<BLOCKS_TOTAL, BLK_THREADS, 0, stream>>>(
            h, src, dst, etype, fwd_rel, partial, n_edges, n_rels);
        const int cgrid = ((n_edges / 4) + 255) / 256;
        combine_kernel<<<cgrid, 256, 0, stream>>>(partial, out, n_edges);
    } else {
        const int grid = (n_edges + 7) / 8;
        distmult_score_kernel<<<grid, 256, 0, stream>>>(
            h, src, dst, etype, fwd_rel, out, n_edges);
    }
}

// Round 5
// 92.955 us; speedup vs baseline: 1.3794x; 1.1506x over previous
//
#include <hip/hip_runtime.h>
#include <hip/hip_fp16.h>

// DistMult forward scoring: score[e] = sum_d h[src,d] * fwd_rel[et,d] * h[dst,d]
// E=640000, D=128, fp32 in/out.
//
// R4: measured limiter is L2 gather delivery (~15 TB/s, ~75% of the
// 8 XCD x 16 ch x 64 B x 2.4 GHz = 19.7 TB/s channel ceiling). Halve the
// bytes: prologue converts h and fwd_rel to fp16 in d_ws. fp16 h table =
// 2.56 MB -> fully L2-resident per XCD with NO dim-split: one main kernel,
// no partials/combine. fp16 fwd_rel (128 KB) staged in LDS. A 16-lane team
// gathers a full 256 B fp16 row at 16 B/lane (coalesced); 4 edges/team/iter
// for MLP; fp32 accumulate; width-16 shuffle reduce; lane 0 stores float4.

typedef unsigned short u16;

constexpr int EMB_DIM  = 128;
constexpr int MAX_RELS = 500;
constexpr int BLOCKS   = 256;    // 1 per CU
constexpr int THREADS  = 1024;   // 64 teams of 16 lanes

// ---- prologue: fp32 -> fp16 pack, 8 floats per thread ----
__global__ __launch_bounds__(256) void convert_fp16_kernel(
    const float* __restrict__ a, u16* __restrict__ a16, int n_a8,
    const float* __restrict__ b, u16* __restrict__ b16, int n_b8)
{
    const int total = n_a8 + n_b8;
    for (int i = blockIdx.x * blockDim.x + threadIdx.x; i < total;
         i += gridDim.x * blockDim.x) {
        const float* s; u16* d; int j;
        if (i < n_a8) { s = a; d = a16; j = i; }
        else          { s = b; d = b16; j = i - n_a8; }
        float4 lo = reinterpret_cast<const float4*>(s)[j * 2];
        float4 hi = reinterpret_cast<const float4*>(s)[j * 2 + 1];
        u16 u0 = __half_as_ushort(__float2half(lo.x));
        u16 u1 = __half_as_ushort(__float2half(lo.y));
        u16 u2 = __half_as_ushort(__float2half(lo.z));
        u16 u3 = __half_as_ushort(__float2half(lo.w));
        u16 u4 = __half_as_ushort(__float2half(hi.x));
        u16 u5 = __half_as_ushort(__float2half(hi.y));
        u16 u6 = __half_as_ushort(__float2half(hi.z));
        u16 u7 = __half_as_ushort(__float2half(hi.w));
        uint4 v;
        v.x = (unsigned)u0 | ((unsigned)u1 << 16);
        v.y = (unsigned)u2 | ((unsigned)u3 << 16);
        v.z = (unsigned)u4 | ((unsigned)u5 << 16);
        v.w = (unsigned)u6 | ((unsigned)u7 << 16);
        reinterpret_cast<uint4*>(d)[j] = v;
    }
}

__device__ __forceinline__ float dot8(uint4 A, uint4 B, uint4 C) {
    const __half2* a2 = reinterpret_cast<const __half2*>(&A);
    const __half2* b2 = reinterpret_cast<const __half2*>(&B);
    const __half2* c2 = reinterpret_cast<const __half2*>(&C);
    float acc = 0.f;
    #pragma unroll
    for (int k = 0; k < 4; ++k) {
        float2 fa = __half22float2(a2[k]);
        float2 fb = __half22float2(b2[k]);
        float2 fc = __half22float2(c2[k]);
        acc += fa.x * fb.x * fc.x + fa.y * fb.y * fc.y;
    }
    return acc;
}

__global__ __launch_bounds__(THREADS) void distmult_fp16_kernel(
    const u16* __restrict__ h16,     // [n_nodes][128] fp16
    const int* __restrict__ src,
    const int* __restrict__ dst,
    const int* __restrict__ etype,
    const u16* __restrict__ w16,     // [n_rels][128] fp16
    float*     __restrict__ out,
    int n_edges, int n_rels)
{
    __shared__ u16 w_lds[MAX_RELS * EMB_DIM];   // 128 KB

    // stage fwd_rel fp16 into LDS (linear, coalesced uint4)
    {
        const int slots = n_rels * (EMB_DIM / 8);     // uint4 slots
        for (int s = threadIdx.x; s < slots; s += THREADS)
            reinterpret_cast<uint4*>(w_lds)[s] =
                reinterpret_cast<const uint4*>(w16)[s];
    }
    __syncthreads();

    const int team = threadIdx.x >> 4;   // 64 teams
    const int lane = threadIdx.x & 15;

    const uint4* hp = reinterpret_cast<const uint4*>(h16) + lane;  // +16/row
    const uint4* wl = reinterpret_cast<const uint4*>(w_lds) + lane;

    const int stride = BLOCKS * (THREADS / 16) * 4;   // 65536 edges/pass

    for (int e0 = (blockIdx.x * (THREADS / 16) + team) * 4; e0 < n_edges;
         e0 += stride) {
        if (e0 + 3 < n_edges) {
            const int4 s4 = *reinterpret_cast<const int4*>(src   + e0);
            const int4 d4 = *reinterpret_cast<const int4*>(dst   + e0);
            const int4 t4 = *reinterpret_cast<const int4*>(etype + e0);

            // 8 L2 gathers: full 256 B fp16 rows, 16 B/lane
            uint4 a0 = hp[(size_t)s4.x * 16];
            uint4 a1 = hp[(size_t)s4.y * 16];
            uint4 a2 = hp[(size_t)s4.z * 16];
            uint4 a3 = hp[(size_t)s4.w * 16];
            uint4 c0 = hp[(size_t)d4.x * 16];
            uint4 c1 = hp[(size_t)d4.y * 16];
            uint4 c2 = hp[(size_t)d4.z * 16];
            uint4 c3 = hp[(size_t)d4.w * 16];
            // 4 LDS reads for w
            uint4 b0 = wl[(size_t)t4.x * 16];
            uint4 b1 = wl[(size_t)t4.y * 16];
            uint4 b2 = wl[(size_t)t4.z * 16];
            uint4 b3 = wl[(size_t)t4.w * 16];

            float acc0 = dot8(a0, b0, c0);
            float acc1 = dot8(a1, b1, c1);
            float acc2 = dot8(a2, b2, c2);
            float acc3 = dot8(a3, b3, c3);

            #pragma unroll
            for (int off = 8; off > 0; off >>= 1) {
                acc0 += __shfl_down(acc0, off, 16);
                acc1 += __shfl_down(acc1, off, 16);
                acc2 += __shfl_down(acc2, off, 16);
                acc3 += __shfl_down(acc3, off, 16);
            }
            if (lane == 0)
                *reinterpret_cast<float4*>(out + e0) =
                    make_float4(acc0, acc1, acc2, acc3);
        } else {
            for (int k = 0; k < 4; ++k) {
                const int e = e0 + k;
                if (e >= n_edges) break;
                uint4 a = hp[(size_t)src[e] * 16];
                uint4 c = hp[(size_t)dst[e] * 16];
                uint4 b = wl[(size_t)etype[e] * 16];
                float acc = dot8(a, b, c);
                #pragma unroll
                for (int off = 8; off > 0; off >>= 1)
                    acc += __shfl_down(acc, off, 16);
                if (lane == 0) out[e] = acc;
            }
        }
    }
}

// fallback: fp32 direct (R0-style) if ws too small or n_rels > MAX_RELS
__global__ __launch_bounds__(256) void distmult_score_kernel(
    const float* __restrict__ h,
    const int*   __restrict__ src,
    const int*   __restrict__ dst,
    const int*   __restrict__ etype,
    const float* __restrict__ fwd_rel,
    float*       __restrict__ out,
    int n_edges)
{
    const int tid  = blockIdx.x * blockDim.x + threadIdx.x;
    const int lane = threadIdx.x & 63;
    const int half = lane >> 5;
    const int sub  = lane & 31;
    const int edge = (tid >> 6) * 2 + half;
    if (edge >= n_edges) return;

    const int s = src[edge];
    const int d = dst[edge];
    const int e = etype[edge];

    const float4 a = reinterpret_cast<const float4*>(h       + (size_t)s * EMB_DIM)[sub];
    const float4 b = reinterpret_cast<const float4*>(fwd_rel + (size_t)e * EMB_DIM)[sub];
    const float4 c = reinterpret_cast<const float4*>(h       + (size_t)d * EMB_DIM)[sub];

    float acc = a.x*b.x*c.x + a.y*b.y*c.y + a.z*b.z*c.z + a.w*b.w*c.w;
    #pragma unroll
    for (int off = 16; off > 0; off >>= 1)
        acc += __shfl_down(acc, off, 32);
    if (sub == 0) out[edge] = acc;
}

extern "C" void kernel_launch(void* const* d_in, const int* in_sizes, int n_in,
                              void* d_out, int out_size, void* d_ws, size_t ws_size,
                              hipStream_t stream) {
    const float* h       = (const float*)d_in[0];
    const int*   src     = (const int*)d_in[1];
    const int*   dst     = (const int*)d_in[2];
    const int*   etype   = (const int*)d_in[3];
    const float* fwd_rel = (const float*)d_in[4];
    float* out = (float*)d_out;

    const int n_edges = in_sizes[1];
    const int n_h     = in_sizes[0];              // n_nodes*128
    const int n_w     = in_sizes[4];              // n_rels*128
    const int n_rels  = n_w / EMB_DIM;
    const size_t need = (size_t)(n_h + n_w) * sizeof(u16);

    if (ws_size >= need && n_rels <= MAX_RELS &&
        (n_h % 8) == 0 && (n_w % 8) == 0) {
        u16* h16 = (u16*)d_ws;
        u16* w16 = h16 + n_h;

        const int n_a8 = n_h / 8, n_b8 = n_w / 8;
        const int cgrid = (n_a8 + n_b8 + 255) / 256;
        convert_fp16_kernel<<<cgrid, 256, 0, stream>>>(
            h, h16, n_a8, fwd_rel, w16, n_b8);

        distmult_fp16_kernel<<<BLOCKS, THREADS, 0, stream>>>(
            h16, src, dst, etype, w16, out, n_edges, n_rels);
    } else {
        const int grid = (n_edges + 7) / 8;
        distmult_score_kernel<<<grid, 256, 0, stream>>>(
            h, src, dst, etype, fwd_rel, out, n_edges);
    }
}